// Round 4
// baseline (283.100 us; speedup 1.0000x reference)
//
#include <hip/hip_runtime.h>

typedef _Float16 f16;
typedef _Float16 f16x8 __attribute__((ext_vector_type(8)));
typedef float f32x4 __attribute__((ext_vector_type(4)));

// async global->LDS, 16B per lane; LDS dest = wave-uniform base + lane*16
#define GLD16(g, l) __builtin_amdgcn_global_load_lds( \
    (const __attribute__((address_space(1))) void*)(g), \
    (__attribute__((address_space(3))) void*)(l), 16, 0, 0)

// ---------------------------------------------------------------------------
// 4-wave generic f16 MFMA GEMM (projections): C[m][n] = sum_k A[m][k]*B[n][k]
// MODE: 1 = bias[col], 2 = bias[row], 3 = split QK (cols<768 -> C, else C2)
// XOR chunk swizzle: 16B chunk slot p of row r holds global chunk p^((r>>1)&3)
// -> fragment ds_read_b128 is bank-conflict-free (R2: SQ_LDS_BANK_CONFLICT=0).
// K-loop: PROVEN two-barrier single-buffer shape (R1/R2 graph-replay-safe).
// ---------------------------------------------------------------------------
template <typename OutT, int BM, int BN, int MODE>
__global__ __launch_bounds__(256, 4)
void gemm_kernel(const f16* __restrict__ A, long sA,
                 const f16* __restrict__ B, long sB,
                 void* __restrict__ Cv, long sC,
                 void* __restrict__ C2v,
                 const float* __restrict__ bias,
                 const float* __restrict__ bias2,
                 int N, int K)
{
    constexpr int FM = BM / 32;
    constexpr int FN = BN / 32;
    constexpr int IA = BM / 64;
    constexpr int IB = BN / 64;
    constexpr int RA = BM / 4;
    constexpr int RB = BN / 4;

    OutT* C  = (OutT*)Cv;
    OutT* C2 = (OutT*)C2v;
    const int tid  = threadIdx.x;
    const int wave = tid >> 6;
    const int lane = tid & 63;
    const int bz   = blockIdx.z;
    A += (long)bz * sA;
    B += (long)bz * sB;
    C += (long)bz * sC;
    const long bm = (long)blockIdx.x * BM;
    const long bn = (long)blockIdx.y * BN;

    __shared__ f16 sAt[BM * 32];
    __shared__ f16 sBt[BN * 32];

    const int srow = lane >> 2;
    const int sc   = lane & 3;
    const int gch  = (sc ^ ((srow >> 1) & 3)) * 8;

    const f16* gA[IA]; const f16* gB[IB];
    f16* lA[IA]; f16* lB[IB];
    #pragma unroll
    for (int i = 0; i < IA; ++i) {
        gA[i] = A + (bm + wave * RA + i * 16 + srow) * (long)K + gch;
        lA[i] = &sAt[(wave * RA + i * 16) * 32];
    }
    #pragma unroll
    for (int i = 0; i < IB; ++i) {
        gB[i] = B + (bn + wave * RB + i * 16 + srow) * (long)K + gch;
        lB[i] = &sBt[(wave * RB + i * 16) * 32];
    }

    const int wm = (wave >> 1) * (BM / 2);
    const int wn = (wave & 1) * (BN / 2);
    const int lr = lane & 15;
    const int qd = lane >> 4;
    const int swz = (qd ^ ((lr >> 1) & 3)) * 8;

    f32x4 acc[FM][FN] = {};

    for (int k0 = 0; k0 < K; k0 += 32) {
        #pragma unroll
        for (int i = 0; i < IA; ++i) { GLD16(gA[i], lA[i]); gA[i] += 32; }
        #pragma unroll
        for (int i = 0; i < IB; ++i) { GLD16(gB[i], lB[i]); gB[i] += 32; }
        __syncthreads();

        f16x8 af[FM], bf[FN];
        #pragma unroll
        for (int t = 0; t < FM; ++t)
            af[t] = *(const f16x8*)&sAt[(wm + t * 16 + lr) * 32 + swz];
        #pragma unroll
        for (int t = 0; t < FN; ++t)
            bf[t] = *(const f16x8*)&sBt[(wn + t * 16 + lr) * 32 + swz];
        #pragma unroll
        for (int tm = 0; tm < FM; ++tm)
            #pragma unroll
            for (int tn = 0; tn < FN; ++tn)
                acc[tm][tn] = __builtin_amdgcn_mfma_f32_16x16x32_f16(
                    af[tm], bf[tn], acc[tm][tn], 0, 0, 0);
        __syncthreads();
    }

    #pragma unroll
    for (int tn = 0; tn < FN; ++tn) {
        const long col = bn + wn + tn * 16 + lr;
        OutT* dst = C;
        long cc = col, stride = N;
        float bc = 0.f;
        if (MODE == 1) bc = bias[col];
        if (MODE == 3) {
            stride = 768;
            if (col >= 768) { dst = C2; cc = col - 768; bc = bias2[cc]; }
            else            { bc = bias[cc]; }
        }
        #pragma unroll
        for (int tm = 0; tm < FM; ++tm) {
            #pragma unroll
            for (int r = 0; r < 4; ++r) {
                const long row = bm + wm + tm * 16 + qd * 4 + r;
                float v = acc[tm][tn][r] + bc;
                if (MODE == 2) v += bias[row];
                dst[row * stride + cc] = (OutT)v;
            }
        }
    }
}

// ---------------------------------------------------------------------------
// Scores: S[b] = Q[b] @ K[b]^T, f16 out. 128x256 tile, 256 threads (4 waves
// 2x2, wave tile 64x128 = 32 MFMA/step). Two-barrier single-buffer K-loop.
// Grid (16, 8, 4) = 512 blocks = 2 blocks/CU. LDS 24 KB.
// ---------------------------------------------------------------------------
__global__ __launch_bounds__(256, 2)
void scores_kernel(const f16* __restrict__ Q, const f16* __restrict__ Km,
                   f16* __restrict__ S)
{
    const int tid  = threadIdx.x;
    const int wave = tid >> 6;
    const int lane = tid & 63;
    const int bz   = blockIdx.z;
    Q  += (long)bz * 2048 * 768;
    Km += (long)bz * 2048 * 768;
    S  += (long)bz * 2048 * 2048;
    const long bm = (long)blockIdx.x * 128;
    const long bn = (long)blockIdx.y * 256;

    __shared__ f16 sA[128 * 32];
    __shared__ f16 sB[256 * 32];

    const int srow = lane >> 2;
    const int sc   = lane & 3;
    const int gch  = (sc ^ ((srow >> 1) & 3)) * 8;

    // A: wave stages rows [wave*32, wave*32+32) : 2 issues
    const f16* gA0 = Q + (bm + wave * 32 + srow) * 768 + gch;
    const f16* gA1 = gA0 + 16 * 768;
    f16* lA0 = &sA[(wave * 32) * 32];
    f16* lA1 = &sA[(wave * 32 + 16) * 32];
    // B: wave stages rows [wave*64, wave*64+64) : 4 issues
    const f16* gB[4]; f16* lB[4];
    #pragma unroll
    for (int i = 0; i < 4; ++i) {
        gB[i] = Km + (bn + wave * 64 + i * 16 + srow) * 768 + gch;
        lB[i] = &sB[(wave * 64 + i * 16) * 32];
    }

    const int wm = (wave >> 1) * 64;
    const int wn = (wave & 1) * 128;
    const int lr = lane & 15;
    const int qd = lane >> 4;
    const int swz = (qd ^ ((lr >> 1) & 3)) * 8;

    f32x4 acc[4][8] = {};

    for (int s = 0; s < 24; ++s) {
        const int ko = s * 32;
        GLD16(gA0 + ko, lA0); GLD16(gA1 + ko, lA1);
        #pragma unroll
        for (int i = 0; i < 4; ++i) GLD16(gB[i] + ko, lB[i]);
        __syncthreads();

        f16x8 af[4], bf[8];
        #pragma unroll
        for (int t = 0; t < 4; ++t)
            af[t] = *(const f16x8*)&sA[(wm + t * 16 + lr) * 32 + swz];
        #pragma unroll
        for (int t = 0; t < 8; ++t)
            bf[t] = *(const f16x8*)&sB[(wn + t * 16 + lr) * 32 + swz];
        #pragma unroll
        for (int tm = 0; tm < 4; ++tm)
            #pragma unroll
            for (int tn = 0; tn < 8; ++tn)
                acc[tm][tn] = __builtin_amdgcn_mfma_f32_16x16x32_f16(
                    af[tm], bf[tn], acc[tm][tn], 0, 0, 0);
        __syncthreads();
    }

    #pragma unroll
    for (int tn = 0; tn < 8; ++tn) {
        const long col = bn + wn + tn * 16 + lr;
        #pragma unroll
        for (int tm = 0; tm < 4; ++tm)
            #pragma unroll
            for (int r = 0; r < 4; ++r) {
                const long row = bm + wm + tm * 16 + qd * 4 + r;
                S[row * 2048 + col] = (f16)acc[tm][tn][r];
            }
    }
}

// ---------------------------------------------------------------------------
// Fused softmax + PV: Y[b][r][c] = sum_k softmax(S[b][r][:])[k] * VT[b][c][k]
// Block: 64 q-rows x 384 out-cols, grid (32, 2, 4) = 256 blocks.
// Phase 1: streaming row stats (max, sum) over the 64-row S strip.
// Phase 2: two-barrier single-buffer K-loop, 32 keys/step; exp(s-m) applied
// on A-frags in-register, normalize by 1/l in the epilogue.
// ---------------------------------------------------------------------------
__global__ __launch_bounds__(256, 2)
void pv_kernel(const f16* __restrict__ S, const f16* __restrict__ VT,
               f16* __restrict__ Y)
{
    const int tid  = threadIdx.x;
    const int wave = tid >> 6;
    const int lane = tid & 63;
    const int bz   = blockIdx.z;
    S  += (long)bz * 2048 * 2048;
    VT += (long)bz * 768 * 2048;
    Y  += (long)bz * 2048 * 768;
    const long r0 = (long)blockIdx.x * 64;
    const long c0 = (long)blockIdx.y * 384;

    __shared__ f16 sS[64 * 32];
    __shared__ f16 sV[384 * 32];
    __shared__ float pm[256], pl[256];
    __shared__ float fm[64], fl[64];

    // ---- Phase 1: row stats (64 rows, 4 threads/row, 512 cols each) ----
    {
        const int rowp = tid >> 2;
        const f16* sp = S + (r0 + rowp) * 2048 + (tid & 3) * 8;
        float m = -3.0e38f, l = 0.f;
        for (int i = 0; i < 64; ++i) {
            f16x8 x = *(const f16x8*)(sp + i * 32);
            float v[8], mx = -3.0e38f;
            #pragma unroll
            for (int j = 0; j < 8; ++j) { v[j] = (float)x[j]; mx = fmaxf(mx, v[j]); }
            if (mx > m) { l *= __expf(m - mx); m = mx; }
            #pragma unroll
            for (int j = 0; j < 8; ++j) l += __expf(v[j] - m);
        }
        pm[tid] = m; pl[tid] = l;
    }
    __syncthreads();
    if (tid < 64) {
        const int b = tid * 4;
        float m = fmaxf(fmaxf(pm[b], pm[b+1]), fmaxf(pm[b+2], pm[b+3]));
        float l = pl[b]   * __expf(pm[b]   - m) + pl[b+1] * __expf(pm[b+1] - m)
                + pl[b+2] * __expf(pm[b+2] - m) + pl[b+3] * __expf(pm[b+3] - m);
        fm[tid] = m; fl[tid] = 1.0f / l;
    }
    __syncthreads();

    // ---- Phase 2: two-barrier K-loop ----
    const int rg = wave >> 1;          // row-group: 32 rows
    const int cg = wave & 1;           // col-group: 192 cols
    const int srow = lane >> 2;
    const int sc   = lane & 3;
    const int gch  = (sc ^ ((srow >> 1) & 3)) * 8;

    // S staging: wave stages rows [wave*16, wave*16+16) : 1 issue
    const f16* gS = S + (r0 + wave * 16 + srow) * 2048 + gch;
    f16* lS = &sS[(wave * 16) * 32];
    // V staging: wave stages rows [wave*96, wave*96+96) : 6 issues
    const f16* gV[6]; f16* lV[6];
    #pragma unroll
    for (int i = 0; i < 6; ++i) {
        gV[i] = VT + (c0 + wave * 96 + i * 16 + srow) * 2048 + gch;
        lV[i] = &sV[(wave * 96 + i * 16) * 32];
    }

    const int lr = lane & 15;
    const int qd = lane >> 4;
    const int swz = (qd ^ ((lr >> 1) & 3)) * 8;

    const float mr0 = fm[rg * 32 + lr];
    const float mr1 = fm[rg * 32 + 16 + lr];

    f32x4 acc[2][12] = {};

    for (int s = 0; s < 64; ++s) {
        const int ko = s * 32;
        GLD16(gS + ko, lS);
        #pragma unroll
        for (int i = 0; i < 6; ++i) GLD16(gV[i] + ko, lV[i]);
        __syncthreads();

        f16x8 af[2];
        {
            f16x8 a0 = *(const f16x8*)&sS[(rg * 32 + lr) * 32 + swz];
            f16x8 a1 = *(const f16x8*)&sS[(rg * 32 + 16 + lr) * 32 + swz];
            #pragma unroll
            for (int j = 0; j < 8; ++j) {
                af[0][j] = (f16)__expf((float)a0[j] - mr0);
                af[1][j] = (f16)__expf((float)a1[j] - mr1);
            }
        }
        f16x8 bf[12];
        #pragma unroll
        for (int t = 0; t < 12; ++t)
            bf[t] = *(const f16x8*)&sV[(cg * 192 + t * 16 + lr) * 32 + swz];
        #pragma unroll
        for (int tm = 0; tm < 2; ++tm)
            #pragma unroll
            for (int tn = 0; tn < 12; ++tn)
                acc[tm][tn] = __builtin_amdgcn_mfma_f32_16x16x32_f16(
                    af[tm], bf[tn], acc[tm][tn], 0, 0, 0);
        __syncthreads();
    }

    // epilogue: Y = acc * (1/l_row)
    #pragma unroll
    for (int tn = 0; tn < 12; ++tn) {
        const long col = c0 + cg * 192 + tn * 16 + lr;
        #pragma unroll
        for (int tm = 0; tm < 2; ++tm)
            #pragma unroll
            for (int r = 0; r < 4; ++r) {
                const int rl = rg * 32 + tm * 16 + qd * 4 + r;
                Y[(r0 + rl) * 768 + col] = (f16)(acc[tm][tn][r] * fl[rl]);
            }
    }
}

// ---------------------------------------------------------------------------
// fp32 -> f16 converts
// ---------------------------------------------------------------------------
__global__ __launch_bounds__(256)
void cvt_kernel(const float* __restrict__ in, f16* __restrict__ out)
{
    const long i = ((long)blockIdx.x * 256 + threadIdx.x) * 8;
    float4 a = *(const float4*)(in + i);
    float4 b = *(const float4*)(in + i + 4);
    f16x8 o;
    o[0] = (f16)a.x; o[1] = (f16)a.y; o[2] = (f16)a.z; o[3] = (f16)a.w;
    o[4] = (f16)b.x; o[5] = (f16)b.y; o[6] = (f16)b.z; o[7] = (f16)b.w;
    *(f16x8*)&out[i] = o;
}

__global__ __launch_bounds__(256)
void cvt4_kernel(const float* __restrict__ w0, const float* __restrict__ w1,
                 const float* __restrict__ w2, const float* __restrict__ w3,
                 f16* __restrict__ out)
{
    const int sel = blockIdx.y;
    const float* in = (sel == 0) ? w0 : (sel == 1) ? w1 : (sel == 2) ? w2 : w3;
    f16* o = out + (long)sel * 589824;
    const long i = ((long)blockIdx.x * 256 + threadIdx.x) * 8;
    float4 a = *(const float4*)(in + i);
    float4 b = *(const float4*)(in + i + 4);
    f16x8 v;
    v[0] = (f16)a.x; v[1] = (f16)a.y; v[2] = (f16)a.z; v[3] = (f16)a.w;
    v[4] = (f16)b.x; v[5] = (f16)b.y; v[6] = (f16)b.z; v[7] = (f16)b.w;
    *(f16x8*)&o[i] = v;
}

// ---------------------------------------------------------------------------
// B=4, S=2048, D=H=768.  ws layout (bytes):
//   x16 @0  (12.6MB) | w16 @12582912 (4.7MB: wq,wk,wv,wo) | Q @17301504
//   K @29884416 | VT @42467328 ([4][768][2048]) | S @55050240 (33.5MB)
//   Y @88604672      total ~101 MB
// ---------------------------------------------------------------------------
extern "C" void kernel_launch(void* const* d_in, const int* in_sizes, int n_in,
                              void* d_out, int out_size, void* d_ws, size_t ws_size,
                              hipStream_t stream)
{
    const float* x  = (const float*)d_in[0];
    const float* wq = (const float*)d_in[1];
    const float* bq = (const float*)d_in[2];
    const float* wk = (const float*)d_in[3];
    const float* bk = (const float*)d_in[4];
    const float* wv = (const float*)d_in[5];
    const float* bv = (const float*)d_in[6];
    const float* wo = (const float*)d_in[7];
    const float* bo = (const float*)d_in[8];

    char* ws = (char*)d_ws;
    f16* x16 = (f16*)(ws + 0);
    f16* w16 = (f16*)(ws + 12582912);
    f16* Q   = (f16*)(ws + 17301504);
    f16* Kb  = (f16*)(ws + 29884416);
    f16* VT  = (f16*)(ws + 42467328);
    f16* S   = (f16*)(ws + 55050240);
    f16* Y   = (f16*)(ws + 88604672);

    f16* wv16 = w16 + 2 * 589824;
    f16* wo16 = w16 + 3 * 589824;

    cvt_kernel<<<3072, 256, 0, stream>>>(x, x16);
    cvt4_kernel<<<dim3(288, 4), 256, 0, stream>>>(wq, wk, wv, wo, w16);

    // fused Q|K projection: B = [wq;wk], N=1536, split outputs
    gemm_kernel<f16, 128, 128, 3><<<dim3(64, 12, 1), 256, 0, stream>>>(
        x16, 0, w16, 0, Q, 0, Kb, bq, bk, 1536, 768);
    // VT[b][h][s] = sum_d wv[h][d] x[b][s][d] + bv[h]   (row-bias)
    gemm_kernel<f16, 64, 128, 2><<<dim3(12, 16, 4), 256, 0, stream>>>(
        wv16, 0, x16, (long)2048 * 768, VT, (long)768 * 2048, nullptr,
        bv, nullptr, 2048, 768);
    // S[b] = Q[b] @ K[b]^T   (128x256 tiles, two-barrier)
    scores_kernel<<<dim3(16, 8, 4), 256, 0, stream>>>(Q, Kb, S);
    // fused softmax + PV -> Y
    pv_kernel<<<dim3(32, 2, 4), 256, 0, stream>>>(S, VT, Y);
    // out = Y @ wo^T + bo (fp32 out)
    gemm_kernel<float, 128, 64, 1><<<dim3(64, 12, 1), 256, 0, stream>>>(
        Y, 0, wo16, 0, (float*)d_out, 0, nullptr, bo, nullptr, 768, 768);
}

// Round 5
// 224.608 us; speedup vs baseline: 1.2604x; 1.2604x over previous
//
#include <hip/hip_runtime.h>

typedef _Float16 f16;
typedef _Float16 f16x8 __attribute__((ext_vector_type(8)));
typedef float f32x4 __attribute__((ext_vector_type(4)));

// async global->LDS, 16B per lane; LDS dest = wave-uniform base + lane*16
#define GLD16(g, l) __builtin_amdgcn_global_load_lds( \
    (const __attribute__((address_space(1))) void*)(g), \
    (__attribute__((address_space(3))) void*)(l), 16, 0, 0)

// ---------------------------------------------------------------------------
// Generic f16 MFMA GEMM, BK=64: C[m][n] = sum_k A[m][k]*B[n][k] (+bias)
// A: [M][K] f16 row-major, B: [N][K] f16 row-major (B^T layout).
// MODE: 0 none, 1 bias[col], 2 bias[row], 3 split-QK (col<768 -> C else C2).
// 256 threads = 4 waves (2x2); wave tile (BM/2)x(BN/2); MFMA 16x16x32_f16,
// two k-groups per K-step. Two-barrier single-buffer K-loop (graph-replay-
// safe, R1/R2/R4-proven). LDS row = 64 f16 = 128 B; XOR swizzle: slot s of
// row r holds global chunk s^(r&7) -> ds_read_b128 perfectly bank-spread
// (2 lanes per 4-bank group per quad). Staging: one GLD16 issue = 8 rows,
// lane -> row lane>>3, slot lane&7, source chunk (lane&7)^(lane>>3).
// MINW = min waves/EU (VGPR cap): big-acc variants need 2.
// ---------------------------------------------------------------------------
template <typename OutT, int BM, int BN, int MODE, int MINW>
__global__ __launch_bounds__(256, MINW)
void gemm_kernel(const f16* __restrict__ A, long sA,
                 const f16* __restrict__ B, long sB,
                 void* __restrict__ Cv, long sC,
                 void* __restrict__ C2v,
                 const float* __restrict__ bias,
                 const float* __restrict__ bias2,
                 int N, int K)
{
    constexpr int FM = BM / 32;   // A-frags per wave (= (BM/2)/16)
    constexpr int FN = BN / 32;
    constexpr int IA = BM / 32;   // A staging issues per wave (= (BM/4)/8)
    constexpr int IB = BN / 32;

    OutT* C  = (OutT*)Cv;
    OutT* C2 = (OutT*)C2v;
    const int tid  = threadIdx.x;
    const int wave = tid >> 6;
    const int lane = tid & 63;
    const int bz   = blockIdx.z;
    A += (long)bz * sA;
    B += (long)bz * sB;
    C += (long)bz * sC;
    const long bm = (long)blockIdx.x * BM;
    const long bn = (long)blockIdx.y * BN;

    __shared__ f16 sAt[BM * 64];
    __shared__ f16 sBt[BN * 64];

    // staging lane map
    const int srow = lane >> 3;                       // 0..7
    const int gch  = ((lane & 7) ^ srow) * 8;         // source chunk (f16 off)

    const f16* gAb = A + (bm + wave * (BM / 4) + srow) * (long)K + gch;
    const f16* gBb = B + (bn + wave * (BN / 4) + srow) * (long)K + gch;

    const int wm = (wave >> 1) * (BM / 2);
    const int wn = (wave & 1) * (BN / 2);
    const int lr = lane & 15;
    const int qd = lane >> 4;
    // reader swizzle per k-group h: slot = (h*4+qd) ^ (lr&7)
    const int swz0 = ((0 * 4 + qd) ^ (lr & 7)) * 8;
    const int swz1 = ((1 * 4 + qd) ^ (lr & 7)) * 8;

    f32x4 acc[FM][FN] = {};

    for (int k0 = 0; k0 < K; k0 += 64) {
        #pragma unroll
        for (int i = 0; i < IA; ++i)
            GLD16(gAb + k0 + (long)i * 8 * K, &sAt[(wave * (BM / 4) + i * 8) * 64]);
        #pragma unroll
        for (int i = 0; i < IB; ++i)
            GLD16(gBb + k0 + (long)i * 8 * K, &sBt[(wave * (BN / 4) + i * 8) * 64]);
        __syncthreads();

        #pragma unroll
        for (int h = 0; h < 2; ++h) {
            const int swz = h ? swz1 : swz0;
            f16x8 af[FM], bf[FN];
            #pragma unroll
            for (int t = 0; t < FM; ++t)
                af[t] = *(const f16x8*)&sAt[(wm + t * 16 + lr) * 64 + swz];
            #pragma unroll
            for (int t = 0; t < FN; ++t)
                bf[t] = *(const f16x8*)&sBt[(wn + t * 16 + lr) * 64 + swz];
            #pragma unroll
            for (int tm = 0; tm < FM; ++tm)
                #pragma unroll
                for (int tn = 0; tn < FN; ++tn)
                    acc[tm][tn] = __builtin_amdgcn_mfma_f32_16x16x32_f16(
                        af[tm], bf[tn], acc[tm][tn], 0, 0, 0);
        }
        __syncthreads();
    }

    // epilogue: C/D layout col = lane&15, row = (lane>>4)*4 + reg
    #pragma unroll
    for (int tn = 0; tn < FN; ++tn) {
        const long col = bn + wn + tn * 16 + lr;
        OutT* dst = C;
        long cc = col, stride = N;
        float bc = 0.f;
        if (MODE == 1) bc = bias[col];
        if (MODE == 3) {
            stride = 768;
            if (col >= 768) { dst = C2; cc = col - 768; bc = bias2[cc]; }
            else            { bc = bias[cc]; }
        }
        #pragma unroll
        for (int tm = 0; tm < FM; ++tm) {
            #pragma unroll
            for (int r = 0; r < 4; ++r) {
                const long row = bm + wm + tm * 16 + qd * 4 + r;
                float v = acc[tm][tn][r] + bc;
                if (MODE == 2) v += bias[row];
                dst[row * stride + cc] = (OutT)v;
            }
        }
    }
}

// ---------------------------------------------------------------------------
// In-place row softmax over f16 scores; one block per row of 2048.
// fp32 math, unscaled (faithful to reference). Proven in R1/R2.
// ---------------------------------------------------------------------------
__global__ __launch_bounds__(256)
void softmax_kernel(f16* __restrict__ S)
{
    const long row = blockIdx.x;
    f16* p = S + row * 2048;
    const int tid  = threadIdx.x;
    const int wave = tid >> 6;
    const int lane = tid & 63;

    f16x8 x = *(const f16x8*)&p[tid * 8];
    float v[8];
    float m = -1e30f;
    #pragma unroll
    for (int j = 0; j < 8; ++j) { v[j] = (float)x[j]; m = fmaxf(m, v[j]); }
    #pragma unroll
    for (int off = 32; off > 0; off >>= 1) m = fmaxf(m, __shfl_down(m, off));

    __shared__ float rm[4], rs[4];
    if (lane == 0) rm[wave] = m;
    __syncthreads();
    m = fmaxf(fmaxf(rm[0], rm[1]), fmaxf(rm[2], rm[3]));

    float s = 0.f;
    #pragma unroll
    for (int j = 0; j < 8; ++j) { v[j] = __expf(v[j] - m); s += v[j]; }
    #pragma unroll
    for (int off = 32; off > 0; off >>= 1) s += __shfl_down(s, off);
    if (lane == 0) rs[wave] = s;
    __syncthreads();
    s = rs[0] + rs[1] + rs[2] + rs[3];
    const float inv = 1.0f / s;

    f16x8 y;
    #pragma unroll
    for (int j = 0; j < 8; ++j) y[j] = (f16)(v[j] * inv);
    *(f16x8*)&p[tid * 8] = y;
}

// ---------------------------------------------------------------------------
// fused fp32 -> f16 convert: blocks [0,3072) do x (6.29M elems),
// blocks [3072, 4224) do the 4 weight matrices (589824 elems each).
// ---------------------------------------------------------------------------
__global__ __launch_bounds__(256)
void cvt_all_kernel(const float* __restrict__ x,
                    const float* __restrict__ w0, const float* __restrict__ w1,
                    const float* __restrict__ w2, const float* __restrict__ w3,
                    f16* __restrict__ x16, f16* __restrict__ w16)
{
    const float* in; f16* out; long i;
    if (blockIdx.x < 3072) {
        in = x; out = x16;
        i = ((long)blockIdx.x * 256 + threadIdx.x) * 8;
    } else {
        const int wb  = blockIdx.x - 3072;          // 0..1151
        const int sel = wb / 288;                   // 288 blocks per weight
        in  = (sel == 0) ? w0 : (sel == 1) ? w1 : (sel == 2) ? w2 : w3;
        out = w16 + (long)sel * 589824;
        i = ((long)(wb - sel * 288) * 256 + threadIdx.x) * 8;
    }
    float4 a = *(const float4*)(in + i);
    float4 b = *(const float4*)(in + i + 4);
    f16x8 o;
    o[0] = (f16)a.x; o[1] = (f16)a.y; o[2] = (f16)a.z; o[3] = (f16)a.w;
    o[4] = (f16)b.x; o[5] = (f16)b.y; o[6] = (f16)b.z; o[7] = (f16)b.w;
    *(f16x8*)&out[i] = o;
}

// ---------------------------------------------------------------------------
// B=4, S=2048, D=H=768.  ws layout (bytes):
//   x16 @0  (12.6MB) | w16 @12582912 (4.7MB: wq,wk,wv,wo) | Q @17301504
//   K @29884416 | VT @42467328 ([4][768][2048]) | S @55050240 (33.5MB)
//   Y @88604672      total ~101 MB
// ---------------------------------------------------------------------------
extern "C" void kernel_launch(void* const* d_in, const int* in_sizes, int n_in,
                              void* d_out, int out_size, void* d_ws, size_t ws_size,
                              hipStream_t stream)
{
    const float* x  = (const float*)d_in[0];
    const float* wq = (const float*)d_in[1];
    const float* bq = (const float*)d_in[2];
    const float* wk = (const float*)d_in[3];
    const float* bk = (const float*)d_in[4];
    const float* wv = (const float*)d_in[5];
    const float* bv = (const float*)d_in[6];
    const float* wo = (const float*)d_in[7];
    const float* bo = (const float*)d_in[8];

    char* ws = (char*)d_ws;
    f16* x16 = (f16*)(ws + 0);
    f16* w16 = (f16*)(ws + 12582912);
    f16* Q   = (f16*)(ws + 17301504);
    f16* Kb  = (f16*)(ws + 29884416);
    f16* VT  = (f16*)(ws + 42467328);
    f16* S   = (f16*)(ws + 55050240);
    f16* Y   = (f16*)(ws + 88604672);

    f16* wv16 = w16 + 2 * 589824;
    f16* wo16 = w16 + 3 * 589824;

    cvt_all_kernel<<<4224, 256, 0, stream>>>(x, wq, wk, wv, wo, x16, w16);

    // fused Q|K projection: B = [wq;wk], N=1536, split outputs (768 blocks)
    gemm_kernel<f16, 128, 128, 3, 3><<<dim3(64, 12, 1), 256, 0, stream>>>(
        x16, 0, w16, 0, Q, 0, Kb, bq, bk, 1536, 768);
    // VT[b][h][s] = sum_d wv[h][d] x[b][s][d] + bv[h]  (row-bias, 768 blocks)
    gemm_kernel<f16, 64, 128, 2, 4><<<dim3(12, 16, 4), 256, 0, stream>>>(
        wv16, 0, x16, (long)2048 * 768, VT, (long)768 * 2048, nullptr,
        bv, nullptr, 2048, 768);
    // S[b] = Q[b] @ K[b]^T  (128x256 tiles, 512 blocks = 2/CU)
    gemm_kernel<f16, 128, 256, 0, 2><<<dim3(16, 8, 4), 256, 0, stream>>>(
        Q, (long)2048 * 768, Kb, (long)2048 * 768, S, (long)2048 * 2048,
        nullptr, nullptr, nullptr, 2048, 768);
    softmax_kernel<<<8192, 256, 0, stream>>>(S);
    // Y[b] = P[b] @ V[b]: A = S, B = VT  (128x64 tiles, 768 blocks, K=2048)
    gemm_kernel<f16, 128, 64, 0, 4><<<dim3(16, 12, 4), 256, 0, stream>>>(
        S, (long)2048 * 2048, VT, (long)768 * 2048, Y, (long)2048 * 768,
        nullptr, nullptr, nullptr, 768, 2048);
    // out = Y @ wo^T + bo (fp32 out, 768 blocks)
    gemm_kernel<float, 128, 64, 1, 4><<<dim3(64, 12, 1), 256, 0, stream>>>(
        Y, 0, wo16, 0, (float*)d_out, 0, nullptr, bo, nullptr, 768, 768);
}